// Round 11
// baseline (862.271 us; speedup 1.0000x reference)
//
#include <hip/hip_runtime.h>
#include <hip/hip_fp16.h>
#include <math.h>

// Problem constants (fixed by setup_inputs)
#define BB 16
#define NIN 2048
#define NC 64
#define NF 16
#define BLOCKS_PER_B 128
#define I_PER_BLOCK (NIN / BLOCKS_PER_B) /* 16 */
#define I_PER_WAVE (I_PER_BLOCK / 4)     /* 4  */
#define NPART (BB * BLOCKS_PER_B)        /* 2048 partial slots of 1024 floats */
// R11 = R10's passing kernels + last-block-per-b fused reduce+squash tails
// (replaces the 3 reduce_squash dispatches; zero added traffic).

__device__ __forceinline__ float dot4(float4 a, float4 b) {
    return a.x * b.x + a.y * b.y + a.z * b.z + a.w * b.w;
}

__device__ __forceinline__ float4 unpack4(unsigned a, unsigned b) {
    __half2 ha = *reinterpret_cast<__half2*>(&a);
    __half2 hb = *reinterpret_cast<__half2*>(&b);
    float2 fa = __half22float2(ha);
    float2 fb = __half22float2(hb);
    return make_float4(fa.x, fa.y, fb.x, fb.y);
}

// Reduce this b's 128 partials (slot tid), add bias, squash, (+prev) -> dst.
// Runs in the LAST block of b. tid groups of 4 share capsule tid>>2.
__device__ __forceinline__ void tail_squash(const float* __restrict__ part,
                                            const float* __restrict__ bias,
                                            const float* __restrict__ prev,
                                            float* __restrict__ dst,
                                            float scale, int b, int tid) {
    const float4* p4 = (const float4*)part + (size_t)(b * BLOCKS_PER_B) * 256 + tid;
    float4 rs = make_float4(0.f, 0.f, 0.f, 0.f);
#pragma unroll 8
    for (int q = 0; q < BLOCKS_PER_B; ++q) {
        float4 f = p4[(size_t)q * 256];
        rs.x += f.x; rs.y += f.y; rs.z += f.z; rs.w += f.w;
    }
    const float4 bv = ((const float4*)bias)[tid];
    float4 s4 = make_float4(rs.x * scale + bv.x, rs.y * scale + bv.y,
                            rs.z * scale + bv.z, rs.w * scale + bv.w);
    float n2 = dot4(s4, s4);
    n2 += __shfl_xor(n2, 1);
    n2 += __shfl_xor(n2, 2);
    const float sc = n2 / (1.0f + n2) / sqrtf(n2 + 1e-8f);
    float4 o = make_float4(s4.x * sc, s4.y * sc, s4.z * sc, s4.w * sc);
    if (prev) {
        float4 p = ((const float4*)prev)[b * 256 + tid];
        o.x += p.x; o.y += p.y; o.z += p.z; o.w += p.w;
    }
    ((float4*)dst)[b * 256 + tid] = o;
}

// Producer->consumer handshake: store partial, fence, count; last block of b
// acquires and runs tail_squash.
__device__ __forceinline__ void tail_handshake(unsigned* __restrict__ cnt,
                                               const float* __restrict__ part,
                                               const float* __restrict__ bias,
                                               const float* __restrict__ prev,
                                               float* __restrict__ dst,
                                               float scale, int b, int tid) {
    __shared__ int isLast;
    __threadfence();  // release: make this block's partial visible device-wide
    __syncthreads();
    if (tid == 0) isLast = (atomicAdd(&cnt[b], 1u) == BLOCKS_PER_B - 1) ? 1 : 0;
    __syncthreads();
    if (isLast) {
        __threadfence();  // acquire
        tail_squash(part, bias, prev, dst, scale, b, tid);
    }
}

// K1: partial sums over this block's 16 i, emit fp16 copy, fused tail.
__global__ __launch_bounds__(256) void pass_mean(const float* __restrict__ in,
                                                 float* __restrict__ part,
                                                 uint2* __restrict__ cp,
                                                 const float* __restrict__ bias,
                                                 float* __restrict__ out0,
                                                 unsigned* __restrict__ cnt) {
    const int b = blockIdx.x >> 7;
    const int blk = blockIdx.x & 127;
    const int lane = threadIdx.x & 63;
    const int wave = threadIdx.x >> 6;
    const float4* in4 = (const float4*)in;

    float4 acc[4];
#pragma unroll
    for (int k = 0; k < 4; ++k) acc[k] = make_float4(0.f, 0.f, 0.f, 0.f);

    const size_t base =
        ((size_t)b * NIN + (size_t)blk * I_PER_BLOCK + (size_t)wave * I_PER_WAVE) * 256;
#pragma unroll
    for (int t = 0; t < I_PER_WAVE; ++t) {
        const float4* p = in4 + base + (size_t)t * 256;
        uint2* q = cp + base + (size_t)t * 256;
#pragma unroll
        for (int k = 0; k < 4; ++k) {
            float4 v = p[lane + (k << 6)];
            acc[k].x += v.x; acc[k].y += v.y; acc[k].z += v.z; acc[k].w += v.w;
            __half2 h0 = __float22half2_rn(make_float2(v.x, v.y));
            __half2 h1 = __float22half2_rn(make_float2(v.z, v.w));
            uint2 u;
            u.x = *reinterpret_cast<unsigned*>(&h0);
            u.y = *reinterpret_cast<unsigned*>(&h1);
            q[lane + (k << 6)] = u;
        }
    }

    __shared__ float4 red[4 * 256];
#pragma unroll
    for (int k = 0; k < 4; ++k) red[wave * 256 + lane + (k << 6)] = acc[k];
    __syncthreads();

    const int t = threadIdx.x;  // float4 slot
    float4 s0 = red[t], s1 = red[256 + t], s2 = red[512 + t], s3 = red[768 + t];
    float4* g = (float4*)(part + (size_t)blockIdx.x * 1024) + t;
    *g = make_float4(s0.x + s1.x + s2.x + s3.x, s0.y + s1.y + s2.y + s3.y,
                     s0.z + s1.z + s2.z + s3.z, s0.w + s1.w + s2.w + s3.w);

    tail_handshake(cnt, part, bias, nullptr, out0, 1.0f / 64.0f, b, t);
}

// K2/K3: capsule-per-lane route (verbatim from R10) + fused tail.
__global__ __launch_bounds__(256) void pass_route(const uint4* __restrict__ cp4,
                                                  const float* __restrict__ wv,
                                                  float* __restrict__ part,
                                                  const float* __restrict__ bias,
                                                  const float* __restrict__ prev,
                                                  float* __restrict__ dst,
                                                  float scale,
                                                  unsigned* __restrict__ cnt) {
    const int b = blockIdx.x >> 7;
    const int blk = blockIdx.x & 127;
    const int lane = threadIdx.x & 63;
    const int wave = threadIdx.x >> 6;
    const float4* wv4 = (const float4*)wv + (size_t)b * 256;

    // weight for capsule `lane`: float4 slots 4l..4l+3
    const float4 w0 = wv4[4 * lane];
    const float4 w1 = wv4[4 * lane + 1];
    const float4 w2 = wv4[4 * lane + 2];
    const float4 w3 = wv4[4 * lane + 3];

    float4 acc0 = make_float4(0.f, 0.f, 0.f, 0.f);
    float4 acc1 = acc0, acc2 = acc0, acc3 = acc0;

    const size_t i0 =
        (size_t)b * NIN + (size_t)blk * I_PER_BLOCK + (size_t)wave * I_PER_WAVE;

    uint4 u[I_PER_WAVE][2];
#pragma unroll
    for (int r = 0; r < I_PER_WAVE; ++r) {
        u[r][0] = cp4[(i0 + r) * 128 + 2 * lane];
        u[r][1] = cp4[(i0 + r) * 128 + 2 * lane + 1];
    }

#pragma unroll
    for (int r = 0; r < I_PER_WAVE; ++r) {
        float4 v0 = unpack4(u[r][0].x, u[r][0].y);
        float4 v1 = unpack4(u[r][0].z, u[r][0].w);
        float4 v2 = unpack4(u[r][1].x, u[r][1].y);
        float4 v3 = unpack4(u[r][1].z, u[r][1].w);
        float d = dot4(v0, w0) + dot4(v1, w1) + dot4(v2, w2) + dot4(v3, w3);
        float e = __expf(d);  // no max shift: |logit| <= ~18, exp safe in fp32
        float ss = e;
        ss += __shfl_xor(ss, 1);
        ss += __shfl_xor(ss, 2);
        ss += __shfl_xor(ss, 4);
        ss += __shfl_xor(ss, 8);
        ss += __shfl_xor(ss, 16);
        ss += __shfl_xor(ss, 32);
        const float a = e / ss;
        acc0.x += a * v0.x; acc0.y += a * v0.y; acc0.z += a * v0.z; acc0.w += a * v0.w;
        acc1.x += a * v1.x; acc1.y += a * v1.y; acc1.z += a * v1.z; acc1.w += a * v1.w;
        acc2.x += a * v2.x; acc2.y += a * v2.y; acc2.z += a * v2.z; acc2.w += a * v2.w;
        acc3.x += a * v3.x; acc3.y += a * v3.y; acc3.z += a * v3.z; acc3.w += a * v3.w;
    }

    // Block reduce over 4 waves; padded stride 20 floats avoids bank alias.
    __shared__ float lds[4 * 64 * 20];
    {
        float* myl = &lds[(wave * 64 + lane) * 20];
        *(float4*)(myl + 0) = acc0;
        *(float4*)(myl + 4) = acc1;
        *(float4*)(myl + 8) = acc2;
        *(float4*)(myl + 12) = acc3;
    }
    __syncthreads();

    const int t = threadIdx.x;
    const int c = t >> 2;   // capsule
    const int j = t & 3;    // feature-group
    float4 s = *(const float4*)&lds[(0 * 64 + c) * 20 + 4 * j];
#pragma unroll
    for (int w = 1; w < 4; ++w) {
        float4 r = *(const float4*)&lds[(w * 64 + c) * 20 + 4 * j];
        s.x += r.x; s.y += r.y; s.z += r.z; s.w += r.w;
    }
    float4* g = (float4*)(part + (size_t)blockIdx.x * 1024) + t;  // c*4+j == t
    *g = s;

    tail_handshake(cnt, part, bias, prev, dst, scale, b, t);
}

extern "C" void kernel_launch(void* const* d_in, const int* in_sizes, int n_in,
                              void* d_out, int out_size, void* d_ws, size_t ws_size,
                              hipStream_t stream) {
    const float* in = (const float*)d_in[0];
    const float* bias = (const float*)d_in[1];
    // num_routing fixed at 3; specialized: priors update is constant along the
    // feature axis => logits_t = dot(in, sum_{s<t} out_s).

    char* ws = (char*)d_ws;
    float* part = (float*)ws;                              // 8 MiB
    float* out0 = (float*)(ws + (8 << 20));                // 64 KiB
    float* osum = (float*)(ws + (8 << 20) + (64 << 10));   // 64 KiB
    unsigned* cnt = (unsigned*)(ws + (8 << 20) + (128 << 10)); // 3*16 u32
    uint2* cp = (uint2*)(ws + (8 << 20) + (192 << 10));    // fp16 copy, 64 MiB

    hipMemsetAsync(cnt, 0, 3 * BB * sizeof(unsigned), stream);

    dim3 grid(NPART), blk(256);
    // K1: mean partials + fp16 copy; last block per b -> out0
    pass_mean<<<grid, blk, 0, stream>>>(in, part, cp, bias, out0, cnt);
    // K2: route with out0; last block per b -> osum = out0 + out1
    pass_route<<<grid, blk, 0, stream>>>((const uint4*)cp, out0, part, bias,
                                         out0, osum, 1.0f, cnt + BB);
    // K3: route with osum; last block per b -> d_out
    pass_route<<<grid, blk, 0, stream>>>((const uint4*)cp, osum, part, bias,
                                         nullptr, (float*)d_out, 1.0f, cnt + 2 * BB);
}

// Round 12
// 80.433 us; speedup vs baseline: 10.7204x; 10.7204x over previous
//
#include <hip/hip_runtime.h>
#include <hip/hip_fp16.h>
#include <math.h>

// Problem constants (fixed by setup_inputs)
#define BB 16
#define NIN 2048
#define NC 64
#define NF 16
#define BLOCKS_PER_B 128
#define I_PER_BLOCK (NIN / BLOCKS_PER_B) /* 16 */
#define I_PER_WAVE (I_PER_BLOCK / 4)     /* 4  */
#define NPART (BB * BLOCKS_PER_B)        /* 2048 partial slots of 1024 floats */
// R12 = R10 verbatim (best measured: 80.75 us). R11's per-block
// __threadfence handshake regressed 10.7x (device fence = L2 drain on
// non-coherent XCD L2s) — reverted.

__device__ __forceinline__ float dot4(float4 a, float4 b) {
    return a.x * b.x + a.y * b.y + a.z * b.z + a.w * b.w;
}

__device__ __forceinline__ float4 unpack4(unsigned a, unsigned b) {
    __half2 ha = *reinterpret_cast<__half2*>(&a);
    __half2 hb = *reinterpret_cast<__half2*>(&b);
    float2 fa = __half22float2(ha);
    float2 fb = __half22float2(hb);
    return make_float4(fa.x, fa.y, fb.x, fb.y);
}

// Pass 0: partial sums over this block's 16 i, AND emit fp16 copy of the input.
__global__ __launch_bounds__(256) void pass_mean(const float* __restrict__ in,
                                                 float* __restrict__ part,
                                                 uint2* __restrict__ cp) {
    const int b = blockIdx.x >> 7;
    const int blk = blockIdx.x & 127;
    const int lane = threadIdx.x & 63;
    const int wave = threadIdx.x >> 6;
    const float4* in4 = (const float4*)in;

    float4 acc[4];
#pragma unroll
    for (int k = 0; k < 4; ++k) acc[k] = make_float4(0.f, 0.f, 0.f, 0.f);

    const size_t base =
        ((size_t)b * NIN + (size_t)blk * I_PER_BLOCK + (size_t)wave * I_PER_WAVE) * 256;
#pragma unroll
    for (int t = 0; t < I_PER_WAVE; ++t) {
        const float4* p = in4 + base + (size_t)t * 256;
        uint2* q = cp + base + (size_t)t * 256;
#pragma unroll
        for (int k = 0; k < 4; ++k) {
            float4 v = p[lane + (k << 6)];
            acc[k].x += v.x; acc[k].y += v.y; acc[k].z += v.z; acc[k].w += v.w;
            __half2 h0 = __float22half2_rn(make_float2(v.x, v.y));
            __half2 h1 = __float22half2_rn(make_float2(v.z, v.w));
            uint2 u;
            u.x = *reinterpret_cast<unsigned*>(&h0);
            u.y = *reinterpret_cast<unsigned*>(&h1);
            q[lane + (k << 6)] = u;
        }
    }

    __shared__ float4 red[4 * 256];
#pragma unroll
    for (int k = 0; k < 4; ++k) red[wave * 256 + lane + (k << 6)] = acc[k];
    __syncthreads();

    const int t = threadIdx.x;  // float4 slot
    float4 s0 = red[t], s1 = red[256 + t], s2 = red[512 + t], s3 = red[768 + t];
    float4* g = (float4*)(part + (size_t)blockIdx.x * 1024) + t;
    *g = make_float4(s0.x + s1.x + s2.x + s3.x, s0.y + s1.y + s2.y + s3.y,
                     s0.z + s1.z + s2.z + s3.z, s0.w + s1.w + s2.w + s3.w);
}

// Routing pass, capsule-per-lane: lane l owns capsule l. Row layout [c][f]
// c-major => lane's 16 fp16 = uint4 pair {2l, 2l+1}. Dot is lane-local;
// softmax over 64 caps = one 6-shfl butterfly (no max shift; |logit|<~18).
__global__ __launch_bounds__(256) void pass_route(const uint4* __restrict__ cp4,
                                                  const float* __restrict__ wv,
                                                  float* __restrict__ part) {
    const int b = blockIdx.x >> 7;
    const int blk = blockIdx.x & 127;
    const int lane = threadIdx.x & 63;
    const int wave = threadIdx.x >> 6;
    const float4* wv4 = (const float4*)wv + (size_t)b * 256;

    // weight for capsule `lane`: float4 slots 4l..4l+3
    const float4 w0 = wv4[4 * lane];
    const float4 w1 = wv4[4 * lane + 1];
    const float4 w2 = wv4[4 * lane + 2];
    const float4 w3 = wv4[4 * lane + 3];

    float4 acc0 = make_float4(0.f, 0.f, 0.f, 0.f);
    float4 acc1 = acc0, acc2 = acc0, acc3 = acc0;

    const size_t i0 =
        (size_t)b * NIN + (size_t)blk * I_PER_BLOCK + (size_t)wave * I_PER_WAVE;

    uint4 u[I_PER_WAVE][2];
#pragma unroll
    for (int r = 0; r < I_PER_WAVE; ++r) {
        u[r][0] = cp4[(i0 + r) * 128 + 2 * lane];
        u[r][1] = cp4[(i0 + r) * 128 + 2 * lane + 1];
    }

#pragma unroll
    for (int r = 0; r < I_PER_WAVE; ++r) {
        float4 v0 = unpack4(u[r][0].x, u[r][0].y);
        float4 v1 = unpack4(u[r][0].z, u[r][0].w);
        float4 v2 = unpack4(u[r][1].x, u[r][1].y);
        float4 v3 = unpack4(u[r][1].z, u[r][1].w);
        float d = dot4(v0, w0) + dot4(v1, w1) + dot4(v2, w2) + dot4(v3, w3);
        float e = __expf(d);
        float ss = e;
        ss += __shfl_xor(ss, 1);
        ss += __shfl_xor(ss, 2);
        ss += __shfl_xor(ss, 4);
        ss += __shfl_xor(ss, 8);
        ss += __shfl_xor(ss, 16);
        ss += __shfl_xor(ss, 32);
        const float a = e / ss;
        acc0.x += a * v0.x; acc0.y += a * v0.y; acc0.z += a * v0.z; acc0.w += a * v0.w;
        acc1.x += a * v1.x; acc1.y += a * v1.y; acc1.z += a * v1.z; acc1.w += a * v1.w;
        acc2.x += a * v2.x; acc2.y += a * v2.y; acc2.z += a * v2.z; acc2.w += a * v2.w;
        acc3.x += a * v3.x; acc3.y += a * v3.y; acc3.z += a * v3.z; acc3.w += a * v3.w;
    }

    // Block reduce over 4 waves. Padded stride 20 floats (80 B) kills the
    // 32-way bank alias a 64-B stride would have.
    __shared__ float lds[4 * 64 * 20];
    {
        float* myl = &lds[(wave * 64 + lane) * 20];
        *(float4*)(myl + 0) = acc0;
        *(float4*)(myl + 4) = acc1;
        *(float4*)(myl + 8) = acc2;
        *(float4*)(myl + 12) = acc3;
    }
    __syncthreads();

    const int t = threadIdx.x;
    const int c = t >> 2;   // capsule
    const int j = t & 3;    // feature-group
    float4 s = *(const float4*)&lds[(0 * 64 + c) * 20 + 4 * j];
#pragma unroll
    for (int w = 1; w < 4; ++w) {
        float4 r = *(const float4*)&lds[(w * 64 + c) * 20 + 4 * j];
        s.x += r.x; s.y += r.y; s.z += r.z; s.w += r.w;
    }
    float4* g = (float4*)(part + (size_t)blockIdx.x * 1024) + (c * 4 + j);
    *g = s;
}

// Reduce 128 partials per b, add bias, squash, optionally add prev.
// grid = 1024 blocks: blockIdx = b*64 + c.
__global__ __launch_bounds__(256) void reduce_squash(const float* __restrict__ part,
                                                     const float* __restrict__ bias,
                                                     const float* __restrict__ prev,
                                                     float* __restrict__ dst,
                                                     float scale) {
    const int b = blockIdx.x >> 6;
    const int c = blockIdx.x & 63;
    const int tid = threadIdx.x;
    const int f = tid & 15;
    const int pc = tid >> 4;  // partial-chunk 0..15

    const float* p = part + (size_t)(b * BLOCKS_PER_B) * 1024 + c * NF + f;
    float sum = 0.f;
#pragma unroll
    for (int j = 0; j < 8; ++j) sum += p[(size_t)(pc + 16 * j) * 1024];

    __shared__ float red[256];
    red[tid] = sum;
    __syncthreads();
    if (tid < 128) red[tid] += red[tid + 128];
    __syncthreads();
    if (tid < 64) red[tid] += red[tid + 64];
    __syncthreads();
    if (tid < 32) red[tid] += red[tid + 32];
    __syncthreads();
    if (tid < 16) {
        float s = (red[tid] + red[tid + 16]) * scale + bias[c * NF + f];
        float n2 = s * s;
        n2 += __shfl_xor(n2, 1);
        n2 += __shfl_xor(n2, 2);
        n2 += __shfl_xor(n2, 4);
        n2 += __shfl_xor(n2, 8);
        const float sc = n2 / (1.0f + n2) / sqrtf(n2 + 1e-8f);
        float o = s * sc;
        const size_t oi = (size_t)b * 1024 + c * NF + f;
        if (prev) o += prev[oi];
        dst[oi] = o;
    }
}

extern "C" void kernel_launch(void* const* d_in, const int* in_sizes, int n_in,
                              void* d_out, int out_size, void* d_ws, size_t ws_size,
                              hipStream_t stream) {
    const float* in = (const float*)d_in[0];
    const float* bias = (const float*)d_in[1];
    // num_routing fixed at 3; specialized: priors update is constant along the
    // feature axis => logits_t = dot(in, sum_{s<t} out_s).

    float* ws = (float*)d_ws;
    float* part = ws;                          // NPART*1024 = 2M floats (8 MB)
    float* out0 = ws + (size_t)NPART * 1024;   // 16384 floats
    float* osum = out0 + 16384;                // 16384 floats
    uint2* cp = (uint2*)(osum + 16384);        // fp16 copy, 64 MB

    dim3 grid(NPART), blk(256);
    // iter 0: uniform agreements -> mean over i; also emit fp16 copy
    pass_mean<<<grid, blk, 0, stream>>>(in, part, cp);
    reduce_squash<<<1024, 256, 0, stream>>>(part, bias, nullptr, out0, 1.0f / 64.0f);
    // iter 1: logits = dot(in, out0)
    pass_route<<<grid, blk, 0, stream>>>((const uint4*)cp, out0, part);
    reduce_squash<<<1024, 256, 0, stream>>>(part, bias, out0, osum, 1.0f);
    // iter 2: logits = dot(in, out0 + out1)
    pass_route<<<grid, blk, 0, stream>>>((const uint4*)cp, osum, part);
    reduce_squash<<<1024, 256, 0, stream>>>(part, bias, nullptr, (float*)d_out, 1.0f);
}